// Round 12
// baseline (498.634 us; speedup 1.0000x reference)
//
#include <hip/hip_runtime.h>
#include <math.h>

// SCQ layer forward.
//   dense+LN f32 double-buffered (per-thread fmaf order unchanged -> Z bits
//   identical to r11) -> Zh/Zl RNE-split planes.
//   score: x3-MFMA on planes + top-2; gap < TAU repaired by exact f32 GEMM
//   (stripe-looped, writes assign directly).
//   small chain: split-K GEMMs with virtual X (sum-of-4-partials operands);
//   NS: closed-form step 1 + 3 GEMM iterations, no xn materialization.
//   Ainv never materialized: mfma<2> epilogue sums Ap partials (same order).
//   prep_c builds Ct/planes/Ch/cn2 and zeroes rcount in one launch.

#define M_ 32768
#define D_ 256
#define K_ 512
#define TAU 0.006f

typedef short bf16x8 __attribute__((ext_vector_type(8)));
typedef unsigned short u16x8 __attribute__((ext_vector_type(8)));
typedef unsigned short u16x4 __attribute__((ext_vector_type(4)));
typedef float f32x4 __attribute__((ext_vector_type(4)));

#define LSTR 56

__device__ inline void split_rne(float f, unsigned short& h, unsigned short& l)
{
    unsigned int u = __float_as_uint(f);
    unsigned int uh = u + (0x7FFFu + ((u >> 16) & 1u));
    h = (unsigned short)(uh >> 16);
    float fh = __uint_as_float(((unsigned int)h) << 16);
    float r = f - fh;
    l = (unsigned short)(__float_as_uint(r) >> 16);
}

__device__ inline unsigned short rne16(float f)
{
    unsigned int u = __float_as_uint(f);
    u += 0x7FFFu + ((u >> 16) & 1u);
    return (unsigned short)(u >> 16);
}

// ---- MFMA GEMM (single bf16): Out = A @ Bt^T, operands as u16 planes -------
// EPI: 2 = + (I - sum4(Ap))[assign[row], col];  3 = Zq + loss partials
template<int EPI>
__global__ __launch_bounds__(256)
void mfma_gemm(const unsigned short* __restrict__ Ah,
               const unsigned short* __restrict__ Bh,
               float* __restrict__ Out, int Kd, int N,
               const float* __restrict__ Ap, const int* __restrict__ assign,
               const float* Zref, float* __restrict__ lossPart)
{
    __shared__ unsigned short sA[128*LSTR];
    __shared__ unsigned short sB[128*LSTR];
    __shared__ float red[256];
    const int tid = threadIdx.x;
    const int m0 = blockIdx.y * 128, n0 = blockIdx.x * 128;
    const int w = tid >> 6, lane = tid & 63;
    const int wr = (w & 1) * 64, wc = (w >> 1) * 64;
    const int cg = lane >> 4, cr = lane & 15;

    f32x4 acc[4][4];
    const f32x4 z4 = {0.f, 0.f, 0.f, 0.f};
#pragma unroll
    for (int i = 0; i < 4; ++i)
#pragma unroll
        for (int j = 0; j < 4; ++j) acc[i][j] = z4;

    const int sr = tid >> 1;
    const int sk = (tid & 1) * 16;
    const int soff = sr * LSTR + sk;
    const unsigned short* Agh = Ah + (size_t)(m0 + sr) * Kd + sk;
    const unsigned short* Bgh = Bh + (size_t)(n0 + sr) * Kd + sk;

    for (int kb = 0; kb < Kd; kb += 32) {
        *(u16x8*)&sA[soff]     = *(const u16x8*)(Agh + kb);
        *(u16x8*)&sA[soff + 8] = *(const u16x8*)(Agh + kb + 8);
        *(u16x8*)&sB[soff]     = *(const u16x8*)(Bgh + kb);
        *(u16x8*)&sB[soff + 8] = *(const u16x8*)(Bgh + kb + 8);
        __syncthreads();
        bf16x8 ah[4], bh[4];
#pragma unroll
        for (int f = 0; f < 4; ++f) {
            ah[f] = *(const bf16x8*)&sA[(wr + f*16 + cr) * LSTR + cg*8];
            bh[f] = *(const bf16x8*)&sB[(wc + f*16 + cr) * LSTR + cg*8];
        }
#pragma unroll
        for (int i = 0; i < 4; ++i)
#pragma unroll
            for (int j = 0; j < 4; ++j)
                acc[i][j] = __builtin_amdgcn_mfma_f32_16x16x32_bf16(ah[i], bh[j], acc[i][j], 0, 0, 0);
        __syncthreads();
    }

    if (EPI == 2) {
#pragma unroll
        for (int i = 0; i < 4; ++i) {
#pragma unroll
            for (int q = 0; q < 4; ++q) {
                const int row = m0 + wr + i*16 + cg*4 + q;
                const int am = assign[row];
#pragma unroll
                for (int j = 0; j < 4; ++j) {
                    const int col = n0 + wc + j*16 + cr;
                    const size_t o = (size_t)am * K_ + col;
                    const float s = Ap[o] + Ap[262144 + o] + Ap[524288 + o] + Ap[786432 + o];
                    const float g = ((am == col) ? 1.f : 0.f) - s;
                    Out[(size_t)row * N + col] = acc[i][j][q] + g;
                }
            }
        }
    } else {
        float lsum = 0.f;
#pragma unroll
        for (int i = 0; i < 4; ++i) {
#pragma unroll
            for (int q = 0; q < 4; ++q) {
                const int row = m0 + wr + i*16 + cg*4 + q;
#pragma unroll
                for (int j = 0; j < 4; ++j) {
                    const int col = n0 + wc + j*16 + cr;
                    const float v = acc[i][j][q];
                    const float zv = Zref[(size_t)row * N + col];
                    const float d = v - zv;
                    lsum += d * d;
                    Out[(size_t)row * N + col] = v;
                }
            }
        }
        red[tid] = lsum;
        __syncthreads();
        for (int s = 128; s > 0; s >>= 1) {
            if (tid < s) red[tid] += red[tid + s];
            __syncthreads();
        }
        if (tid == 0) lossPart[blockIdx.y * gridDim.x + blockIdx.x] = red[0];
    }
}

// -------- score: x3 MFMA on pre-split planes + per-row per-stripe top-2 -----
__global__ __launch_bounds__(256)
void score_mfma_argmin(const unsigned short* __restrict__ Zh, const unsigned short* __restrict__ Zl,
                       const unsigned short* __restrict__ Bth, const unsigned short* __restrict__ Btl,
                       const float* __restrict__ cn2, const float* __restrict__ zn2,
                       float* __restrict__ PV, float* __restrict__ PB,
                       int* __restrict__ PI)
{
    __shared__ unsigned short sAh[128*LSTR], sAl[128*LSTR];
    __shared__ unsigned short sBh[128*LSTR], sBl[128*LSTR];
    __shared__ float l1v[128][2], l2v[128][2];
    __shared__ int   liv[128][2];
    const int tid = threadIdx.x;
    const int m0 = blockIdx.y * 128, n0 = blockIdx.x * 128;
    const int w = tid >> 6, lane = tid & 63;
    const int wr = (w & 1) * 64, wc = (w >> 1) * 64;
    const int cg = lane >> 4, cr = lane & 15;

    f32x4 acc[4][4];
    const f32x4 z4 = {0.f, 0.f, 0.f, 0.f};
#pragma unroll
    for (int i = 0; i < 4; ++i)
#pragma unroll
        for (int j = 0; j < 4; ++j) acc[i][j] = z4;

    const int sr = tid >> 1;
    const int sk = (tid & 1) * 16;
    const int soff = sr * LSTR + sk;
    const unsigned short* Ah = Zh  + (size_t)(m0 + sr) * D_ + sk;
    const unsigned short* Al = Zl  + (size_t)(m0 + sr) * D_ + sk;
    const unsigned short* Bh = Bth + (size_t)(n0 + sr) * D_ + sk;
    const unsigned short* Bl = Btl + (size_t)(n0 + sr) * D_ + sk;

    for (int kb = 0; kb < D_; kb += 32) {
        *(u16x8*)&sAh[soff]     = *(const u16x8*)(Ah + kb);
        *(u16x8*)&sAh[soff + 8] = *(const u16x8*)(Ah + kb + 8);
        *(u16x8*)&sAl[soff]     = *(const u16x8*)(Al + kb);
        *(u16x8*)&sAl[soff + 8] = *(const u16x8*)(Al + kb + 8);
        *(u16x8*)&sBh[soff]     = *(const u16x8*)(Bh + kb);
        *(u16x8*)&sBh[soff + 8] = *(const u16x8*)(Bh + kb + 8);
        *(u16x8*)&sBl[soff]     = *(const u16x8*)(Bl + kb);
        *(u16x8*)&sBl[soff + 8] = *(const u16x8*)(Bl + kb + 8);
        __syncthreads();
        bf16x8 ah[4], al[4], bh[4], bl[4];
#pragma unroll
        for (int f = 0; f < 4; ++f) {
            const int ao = (wr + f*16 + cr) * LSTR + cg*8;
            ah[f] = *(const bf16x8*)&sAh[ao];
            al[f] = *(const bf16x8*)&sAl[ao];
            const int bo = (wc + f*16 + cr) * LSTR + cg*8;
            bh[f] = *(const bf16x8*)&sBh[bo];
            bl[f] = *(const bf16x8*)&sBl[bo];
        }
#pragma unroll
        for (int i = 0; i < 4; ++i)
#pragma unroll
            for (int j = 0; j < 4; ++j) {
                acc[i][j] = __builtin_amdgcn_mfma_f32_16x16x32_bf16(ah[i], bh[j], acc[i][j], 0, 0, 0);
                acc[i][j] = __builtin_amdgcn_mfma_f32_16x16x32_bf16(al[i], bh[j], acc[i][j], 0, 0, 0);
                acc[i][j] = __builtin_amdgcn_mfma_f32_16x16x32_bf16(ah[i], bl[j], acc[i][j], 0, 0, 0);
            }
        __syncthreads();
    }

    const int half = wc >> 6;
#pragma unroll
    for (int i = 0; i < 4; ++i) {
#pragma unroll
        for (int q = 0; q < 4; ++q) {
            const int rl = wr + i*16 + cg*4 + q;
            const float zr = zn2[m0 + rl];
            float b1 = 3.4e38f, b2 = 3.4e38f; int i1 = 0x7fffffff;
#pragma unroll
            for (int j = 0; j < 4; ++j) {
                const int col = n0 + wc + j*16 + cr;
                const float d = (zr + cn2[col]) - 2.0f * acc[i][j][q];
                if (d < b1 || (d == b1 && col < i1)) { b2 = b1; b1 = d; i1 = col; }
                else if (d < b2) b2 = d;
            }
#pragma unroll
            for (int off = 1; off < 16; off <<= 1) {
                const float o1 = __shfl_xor(b1, off);
                const int   oi = __shfl_xor(i1, off);
                const float o2 = __shfl_xor(b2, off);
                if (o1 < b1 || (o1 == b1 && oi < i1)) { b2 = fminf(b1, o2); b1 = o1; i1 = oi; }
                else { b2 = fminf(o1, b2); }
            }
            if (cr == 0) { l1v[rl][half] = b1; l2v[rl][half] = b2; liv[rl][half] = i1; }
        }
    }
    __syncthreads();
    if (tid < 128) {
        const float a1 = l1v[tid][0], a2 = l2v[tid][0]; const int ai = liv[tid][0];
        const float c1 = l1v[tid][1], c2 = l2v[tid][1]; const int ci = liv[tid][1];
        float b1, b2; int bi;
        if (c1 < a1 || (c1 == a1 && ci < ai)) { b1 = c1; bi = ci; b2 = fminf(a1, c2); }
        else { b1 = a1; bi = ai; b2 = fminf(c1, a2); }
        const size_t o = (size_t)(m0 + tid) * 4 + blockIdx.x;
        PV[o] = b1; PB[o] = b2; PI[o] = bi;
    }
}

__global__ void argmin_reduce4(const float* __restrict__ PV, const float* __restrict__ PB,
                               const int* __restrict__ PI, int* __restrict__ assign,
                               int* __restrict__ rlist, int* __restrict__ rcount)
{
    const int m = blockIdx.x * 256 + threadIdx.x;
    float b1 = PV[(size_t)m*4], b2 = PB[(size_t)m*4]; int i1 = PI[(size_t)m*4];
#pragma unroll
    for (int s = 1; s < 4; ++s) {
        const float o1 = PV[(size_t)m*4+s], o2 = PB[(size_t)m*4+s];
        const int oi = PI[(size_t)m*4+s];
        if (o1 < b1 || (o1 == b1 && oi < i1)) { b2 = fminf(b1, o2); b1 = o1; i1 = oi; }
        else { b2 = fminf(o1, b2); }
    }
    assign[m] = i1;
    if (b2 - b1 < TAU) { const int p = atomicAdd(rcount, 1); rlist[p] = m; }
}

// -------- compacted f32 rescoring (stripe-looped), writes assign ------------
__global__ __launch_bounds__(256)
void repair_gemm(const float* __restrict__ Z, const float* __restrict__ B,
                 const float* __restrict__ cn2, const float* __restrict__ zn2,
                 const int* __restrict__ rlist, const int* __restrict__ rcount,
                 int* __restrict__ assign)
{
    const int n = rcount[0];
    const int m0 = blockIdx.x * 128;
    if (m0 >= n) return;
    __shared__ float As[16][132];
    __shared__ float Bs[16][128];
    __shared__ int rows_s[128];
    __shared__ float rbv[128];
    __shared__ int   rbi[128];
    const int tid = threadIdx.x;
    const int tx = tid & 15, ty = tid >> 4;

    if (tid < 128) {
        rows_s[tid] = (m0 + tid < n) ? rlist[m0 + tid] : rlist[0];
        rbv[tid] = 3.4e38f; rbi[tid] = 0x7fffffff;
    }
    __syncthreads();

    const int ar = tid >> 1, ac = (tid & 1) * 8;
    const int br = tid >> 4, bc = (tid & 15) * 8;
    const float* Apt = Z + (size_t)rows_s[ar] * D_ + ac;

    for (int ns = 0; ns < 4; ++ns) {
        const int n0 = ns * 128;
        float acc[8][8];
#pragma unroll
        for (int i = 0; i < 8; ++i)
#pragma unroll
            for (int j = 0; j < 8; ++j) acc[i][j] = 0.f;
        const float* Bp = B + (size_t)br * K_ + n0 + bc;

        for (int kb = 0; kb < D_; kb += 16) {
            float4 a0 = *(const float4*)(Apt + kb);
            float4 a1 = *(const float4*)(Apt + kb + 4);
            float4 b0 = *(const float4*)(Bp + (size_t)kb * K_);
            float4 b1 = *(const float4*)(Bp + (size_t)kb * K_ + 4);
            As[ac+0][ar] = a0.x; As[ac+1][ar] = a0.y; As[ac+2][ar] = a0.z; As[ac+3][ar] = a0.w;
            As[ac+4][ar] = a1.x; As[ac+5][ar] = a1.y; As[ac+6][ar] = a1.z; As[ac+7][ar] = a1.w;
            *(float4*)&Bs[br][bc]     = b0;
            *(float4*)&Bs[br][bc + 4] = b1;
            __syncthreads();
#pragma unroll
            for (int kk = 0; kk < 16; ++kk) {
                float4 av0 = *(const float4*)&As[kk][ty*4];
                float4 av1 = *(const float4*)&As[kk][64 + ty*4];
                float4 bv0 = *(const float4*)&Bs[kk][tx*4];
                float4 bv1 = *(const float4*)&Bs[kk][64 + tx*4];
                float a_[8] = {av0.x, av0.y, av0.z, av0.w, av1.x, av1.y, av1.z, av1.w};
                float b_[8] = {bv0.x, bv0.y, bv0.z, bv0.w, bv1.x, bv1.y, bv1.z, bv1.w};
#pragma unroll
                for (int i = 0; i < 8; ++i)
#pragma unroll
                    for (int j = 0; j < 8; ++j)
                        acc[i][j] = fmaf(a_[i], b_[j], acc[i][j]);
            }
            __syncthreads();
        }

#pragma unroll
        for (int hi = 0; hi < 2; ++hi) {
#pragma unroll
            for (int i = 0; i < 4; ++i) {
                const int rl = hi*64 + ty*4 + i;
                if (m0 + rl >= n) continue;
                const float zr = zn2[rows_s[rl]];
                float best = 3.4e38f; int bi = 0x7fffffff;
#pragma unroll
                for (int hj = 0; hj < 2; ++hj) {
#pragma unroll
                    for (int j = 0; j < 4; ++j) {
                        const int col = n0 + hj*64 + tx*4 + j;
                        const float t1 = zr + cn2[col];
                        const float d  = t1 - 2.0f * acc[hi*4+i][hj*4+j];
                        if (d < best) { best = d; bi = col; }
                    }
                }
#pragma unroll
                for (int off = 1; off < 16; off <<= 1) {
                    const float ov = __shfl_xor(best, off);
                    const int   oi = __shfl_xor(bi, off);
                    if (ov < best || (ov == best && oi < bi)) { best = ov; bi = oi; }
                }
                if (tx == 0) {
                    if (best < rbv[rl] || (best == rbv[rl] && bi < rbi[rl])) {
                        rbv[rl] = best; rbi[rl] = bi;
                    }
                }
            }
        }
        __syncthreads();
    }
    if (tid < 128 && m0 + tid < n) assign[rows_s[tid]] = rbi[tid];
}

// ------- fused dense (64x256, double-buffered) + LayerNorm + Z planes -------
__global__ __launch_bounds__(256)
void dense_ln_kernel(const float* __restrict__ A, const float* __restrict__ Bw,
                     const float* __restrict__ bias, const float* __restrict__ gamma,
                     const float* __restrict__ beta, float* __restrict__ Z,
                     float* __restrict__ zn2,
                     unsigned short* __restrict__ Zh, unsigned short* __restrict__ Zl)
{
    __shared__ float As[2][16][68];
    __shared__ float Bs[2][16][260];
    __shared__ float rred[64][17];
    __shared__ float rstat[64];
    const int tid = threadIdx.x, tx = tid & 15, ty = tid >> 4;
    const int m0 = blockIdx.x * 64;
    float acc[4][16];
#pragma unroll
    for (int i = 0; i < 4; ++i)
#pragma unroll
        for (int j = 0; j < 16; ++j) acc[i][j] = 0.f;

    const int ar = tid >> 2, ac = (tid & 3) * 4;
    const int br = tid >> 4, bc = (tid & 15) * 16;

#define DL_STAGE(buf, kb) { \
    float4 a = *(const float4*)(A + (size_t)(m0 + ar) * 256 + (kb) + ac); \
    As[buf][ac+0][ar] = a.x; As[buf][ac+1][ar] = a.y; \
    As[buf][ac+2][ar] = a.z; As[buf][ac+3][ar] = a.w; \
    _Pragma("unroll") \
    for (int q = 0; q < 4; ++q) \
        *(float4*)&Bs[buf][br][bc + q*4] = \
            *(const float4*)(Bw + (size_t)((kb) + br) * 256 + bc + q*4); }

    DL_STAGE(0, 0)
    __syncthreads();
    for (int t16 = 0; t16 < 16; ++t16) {
        const int cur = t16 & 1;
        if (t16 < 15) DL_STAGE(cur ^ 1, (t16 + 1) * 16)
#pragma unroll
        for (int kk = 0; kk < 16; ++kk) {
            float4 a4 = *(const float4*)&As[cur][kk][ty*4];
            float av[4] = {a4.x, a4.y, a4.z, a4.w};
            float bv[16];
#pragma unroll
            for (int q = 0; q < 4; ++q) {
                float4 b4 = *(const float4*)&Bs[cur][kk][q*64 + tx*4];
                bv[q*4+0] = b4.x; bv[q*4+1] = b4.y; bv[q*4+2] = b4.z; bv[q*4+3] = b4.w;
            }
#pragma unroll
            for (int i = 0; i < 4; ++i)
#pragma unroll
                for (int j = 0; j < 16; ++j)
                    acc[i][j] = fmaf(av[i], bv[j], acc[i][j]);
        }
        __syncthreads();
    }
#undef DL_STAGE

    float bcol[16];
#pragma unroll
    for (int q = 0; q < 4; ++q) {
        float4 b4 = *(const float4*)(bias + q*64 + tx*4);
        bcol[q*4+0] = b4.x; bcol[q*4+1] = b4.y; bcol[q*4+2] = b4.z; bcol[q*4+3] = b4.w;
    }
#pragma unroll
    for (int i = 0; i < 4; ++i)
#pragma unroll
        for (int j = 0; j < 16; ++j) acc[i][j] += bcol[j];

#pragma unroll
    for (int i = 0; i < 4; ++i) {
        float s = 0.f;
#pragma unroll
        for (int j = 0; j < 16; ++j) s += acc[i][j];
        rred[ty*4+i][tx] = s;
    }
    __syncthreads();
    if (tid < 64) {
        float s = 0.f;
#pragma unroll
        for (int t = 0; t < 16; ++t) s += rred[tid][t];
        rstat[tid] = s * (1.f / 256.f);
    }
    __syncthreads();
    float mean_[4];
#pragma unroll
    for (int i = 0; i < 4; ++i) mean_[i] = rstat[ty*4+i];

#pragma unroll
    for (int i = 0; i < 4; ++i) {
        float s = 0.f;
#pragma unroll
        for (int j = 0; j < 16; ++j) { float d = acc[i][j] - mean_[i]; s += d * d; }
        rred[ty*4+i][tx] = s;
    }
    __syncthreads();
    if (tid < 64) {
        float s = 0.f;
#pragma unroll
        for (int t = 0; t < 16; ++t) s += rred[tid][t];
        rstat[tid] = s * (1.f / 256.f);
    }
    __syncthreads();
    float rstd_[4];
#pragma unroll
    for (int i = 0; i < 4; ++i) rstd_[i] = sqrtf(rstat[ty*4+i] + 1e-5f);

    float gam[16], bet[16];
#pragma unroll
    for (int q = 0; q < 4; ++q) {
        float4 g4 = *(const float4*)(gamma + q*64 + tx*4);
        float4 e4 = *(const float4*)(beta  + q*64 + tx*4);
        gam[q*4+0] = g4.x; gam[q*4+1] = g4.y; gam[q*4+2] = g4.z; gam[q*4+3] = g4.w;
        bet[q*4+0] = e4.x; bet[q*4+1] = e4.y; bet[q*4+2] = e4.z; bet[q*4+3] = e4.w;
    }
#pragma unroll
    for (int i = 0; i < 4; ++i)
#pragma unroll
        for (int j = 0; j < 16; ++j) {
            const float d = acc[i][j] - mean_[i];
            acc[i][j] = gam[j] * (d / rstd_[i]) + bet[j];
        }

#pragma unroll
    for (int i = 0; i < 4; ++i) {
        float s = 0.f;
#pragma unroll
        for (int j = 0; j < 16; ++j) s += acc[i][j] * acc[i][j];
        rred[ty*4+i][tx] = s;
    }
    __syncthreads();
    if (tid < 64) {
        float s = 0.f;
#pragma unroll
        for (int t = 0; t < 16; ++t) s += rred[tid][t];
        zn2[m0 + tid] = s;
    }

#pragma unroll
    for (int i = 0; i < 4; ++i) {
        const int row = m0 + ty*4 + i;
#pragma unroll
        for (int q = 0; q < 4; ++q) {
            float4 v;
            v.x = acc[i][q*4+0]; v.y = acc[i][q*4+1];
            v.z = acc[i][q*4+2]; v.w = acc[i][q*4+3];
            const size_t pos = (size_t)row * 256 + q*64 + tx*4;
            *(float4*)(Z + pos) = v;
            unsigned short h[4], l[4];
            split_rne(v.x, h[0], l[0]); split_rne(v.y, h[1], l[1]);
            split_rne(v.z, h[2], l[2]); split_rne(v.w, h[3], l[3]);
            *(u16x4*)(Zh + pos) = *(u16x4*)h;
            *(u16x4*)(Zl + pos) = *(u16x4*)l;
        }
    }
}

// ---------------- split-K small GEMM: 64x64 tiles, grid.z = 4 slices --------
// ASUM: 0 plain; 1 sum of 4 partials; 2 sum of 4 partials + I.
// BSUM: 0 plain; 1 sum of 4 partials.
// OEPI: 0 partial write; 1 NS-fold: out[z] = (z==0 ? 2*sum4(Xprev) : 0) - acc
template<int TRA, int ASUM, int BSUM, int OEPI>
__global__ __launch_bounds__(256)
void sk_gemm(const float* __restrict__ A, const float* __restrict__ B,
             float* __restrict__ Out, int M, int N, int Kd,
             const float* __restrict__ Xprev)
{
    __shared__ float As[16][68];
    __shared__ float Bs[16][68];
    const int tid = threadIdx.x;
    const int tx = tid & 15, ty = tid >> 4;
    const int n0 = blockIdx.x * 64, m0 = blockIdx.y * 64;
    const int kw = Kd >> 2;
    const int kb0 = blockIdx.z * kw;
    const size_t aP = (size_t)M * Kd;
    const size_t bP = (size_t)Kd * N;
    float acc[4][4];
#pragma unroll
    for (int i = 0; i < 4; ++i)
#pragma unroll
        for (int j = 0; j < 4; ++j) acc[i][j] = 0.f;

    for (int kb = kb0; kb < kb0 + kw; kb += 16) {
        if (TRA == 0) {
            const int ar2 = tid >> 2, ac2 = (tid & 3) * 4;
            const size_t off = (size_t)(m0 + ar2) * Kd + kb + ac2;
            float4 a;
            if (ASUM) {
                float4 a0 = *(const float4*)(A + off);
                float4 a1 = *(const float4*)(A + aP + off);
                float4 a2 = *(const float4*)(A + 2*aP + off);
                float4 a3 = *(const float4*)(A + 3*aP + off);
                a.x = a0.x + a1.x + a2.x + a3.x;
                a.y = a0.y + a1.y + a2.y + a3.y;
                a.z = a0.z + a1.z + a2.z + a3.z;
                a.w = a0.w + a1.w + a2.w + a3.w;
                if (ASUM == 2) {
                    const int row = m0 + ar2, colb = kb + ac2;
                    if (row == colb)     a.x += 1.f;
                    if (row == colb + 1) a.y += 1.f;
                    if (row == colb + 2) a.z += 1.f;
                    if (row == colb + 3) a.w += 1.f;
                }
            } else {
                a = *(const float4*)(A + off);
            }
            As[ac2+0][ar2] = a.x; As[ac2+1][ar2] = a.y;
            As[ac2+2][ar2] = a.z; As[ac2+3][ar2] = a.w;
        } else {
            const int ar2 = tid >> 4, ac2 = (tid & 15) * 4;
            float4 a = *(const float4*)(A + (size_t)(kb + ar2) * M + m0 + ac2);
            *(float4*)&As[ar2][ac2] = a;
        }
        {
            const int br2 = tid >> 4, bc2 = (tid & 15) * 4;
            const size_t off = (size_t)(kb + br2) * N + n0 + bc2;
            float4 b;
            if (BSUM) {
                float4 b0 = *(const float4*)(B + off);
                float4 b1 = *(const float4*)(B + bP + off);
                float4 b2 = *(const float4*)(B + 2*bP + off);
                float4 b3 = *(const float4*)(B + 3*bP + off);
                b.x = b0.x + b1.x + b2.x + b3.x;
                b.y = b0.y + b1.y + b2.y + b3.y;
                b.z = b0.z + b1.z + b2.z + b3.z;
                b.w = b0.w + b1.w + b2.w + b3.w;
            } else {
                b = *(const float4*)(B + off);
            }
            *(float4*)&Bs[br2][bc2] = b;
        }
        __syncthreads();
#pragma unroll
        for (int kk = 0; kk < 16; ++kk) {
            float4 a4 = *(const float4*)&As[kk][ty*4];
            float4 b4 = *(const float4*)&Bs[kk][tx*4];
            float a_[4] = {a4.x, a4.y, a4.z, a4.w};
            float b_[4] = {b4.x, b4.y, b4.z, b4.w};
#pragma unroll
            for (int i = 0; i < 4; ++i)
#pragma unroll
                for (int j = 0; j < 4; ++j)
                    acc[i][j] = fmaf(a_[i], b_[j], acc[i][j]);
        }
        __syncthreads();
    }
    const size_t MN = (size_t)M * N;
    float* Op = Out + (size_t)blockIdx.z * MN;
#pragma unroll
    for (int i = 0; i < 4; ++i)
#pragma unroll
        for (int j = 0; j < 4; ++j) {
            const size_t idx = (size_t)(m0 + ty*4 + i) * N + n0 + tx*4 + j;
            if (OEPI == 0) {
                Op[idx] = acc[i][j];
            } else {
                float base = 0.f;
                if (blockIdx.z == 0)
                    base = 2.f * (Xprev[idx] + Xprev[MN + idx] +
                                  Xprev[2*MN + idx] + Xprev[3*MN + idx]);
                Op[idx] = base - acc[i][j];
            }
        }
}

// --------- prep_c: Ct + RNE planes + Ch + cn2 + rcount zero -----------------
__global__ __launch_bounds__(256)
void prep_c(const float* __restrict__ C, float* __restrict__ Ct,
            unsigned short* __restrict__ Cth, unsigned short* __restrict__ Ctl,
            unsigned short* __restrict__ Ch, float* __restrict__ cn2,
            int* __restrict__ rcount)
{
    __shared__ float red[256];
    const int k = blockIdx.x, t = threadIdx.x;
    const float v = C[(size_t)t * K_ + k];
    Ct[k * 256 + t] = v;
    unsigned short h, l;
    split_rne(v, h, l);
    Cth[k * 256 + t] = h;
    Ctl[k * 256 + t] = l;
    Ch[(size_t)t * K_ + k] = h;
    red[t] = v * v;
    __syncthreads();
    for (int s = 128; s > 0; s >>= 1) { if (t < s) red[t] += red[t + s]; __syncthreads(); }
    if (t == 0) {
        cn2[k] = red[0];
        if (k == 0) rcount[0] = 0;
    }
}

__global__ void rowabs_kernel(const float* __restrict__ Sp, float* __restrict__ rowAbs)
{
    __shared__ float red[256];
    const int r = blockIdx.x, t = threadIdx.x;
    const int idx = r * 256 + t;
    float v = Sp[idx] + Sp[65536 + idx] + Sp[131072 + idx] + Sp[196608 + idx];
    if (r == t) v += 1.f;
    red[t] = fabsf(v); __syncthreads();
    for (int s = 128; s > 0; s >>= 1) {
        if (t < s) red[t] += red[t + s];
        __syncthreads();
    }
    if (t == 0) rowAbs[r] = red[0];
}

// X1 = 2cI - c^2 S written as 4 partial slices (slice0 = X1, rest 0)
__global__ void x1_init(const float* __restrict__ rowAbs, const float* __restrict__ Sp,
                        float* __restrict__ Xp)
{
    __shared__ float red[256];
    const int t = threadIdx.x;
    red[t] = rowAbs[t]; __syncthreads();
    for (int s = 128; s > 0; s >>= 1) {
        if (t < s) red[t] = fmaxf(red[t], red[t + s]);
        __syncthreads();
    }
    const float c = 2.f / (1.f + red[0]);
    const int idx = blockIdx.x * 256 + t;
    const int i = idx >> 8, j = idx & 255;
    float s4 = Sp[idx] + Sp[65536 + idx] + Sp[131072 + idx] + Sp[196608 + idx];
    if (i == j) s4 += 1.f;
    const float tt = c * s4;
    const float xp = c * tt;
    Xp[idx] = ((i == j) ? 2.f * c : 0.f) - xp;
    Xp[65536 + idx]  = 0.f;
    Xp[131072 + idx] = 0.f;
    Xp[196608 + idx] = 0.f;
}

// -------- merged: Uth reduce (blocks 0..511) + diversity (blocks 512..767) --
__global__ __launch_bounds__(256)
void gut_reduce(const float* __restrict__ Up, unsigned short* __restrict__ Uth,
                const float* __restrict__ Gp, const float* __restrict__ cn2,
                float* __restrict__ divPart)
{
    __shared__ float red[256];
    __shared__ float rsn[512];
    const int b = blockIdx.x, t = threadIdx.x;
    if (b < 512) {
        const int idx = b * 256 + t;
        Uth[idx] = rne16(Up[idx] + Up[131072 + idx] + Up[262144 + idx] + Up[393216 + idx]);
        return;
    }
    const int gb = b - 512;
    rsn[t]       = 1.f / sqrtf(fmaxf(cn2[t], 1e-12f));
    rsn[t + 256] = 1.f / sqrtf(fmaxf(cn2[t + 256], 1e-12f));
    __syncthreads();
    float dsum = 0.f;
#pragma unroll
    for (int e = 0; e < 4; ++e) {
        const int idx = gb * 1024 + e * 256 + t;
        const int i = idx >> 9, j = idx & 511;
        const float g = Gp[idx] + Gp[262144 + idx] + Gp[524288 + idx] + Gp[786432 + idx];
        if (i != j) dsum += fmaxf(g * rsn[i] * rsn[j], 0.f);
    }
    red[t] = dsum; __syncthreads();
    for (int s = 128; s > 0; s >>= 1) {
        if (t < s) red[t] += red[t + s];
        __syncthreads();
    }
    if (t == 0) divPart[gb] = red[0];
}

// ------- simplex projection (Michelot) fused with column sums + Ph plane ----
__global__ __launch_bounds__(1024)
void project_colsum_kernel(float* P, unsigned short* __restrict__ Ph,
                           float* __restrict__ part)
{
    __shared__ float ps[16][512];
    const int wave = threadIdx.x >> 6;
    const int lane = threadIdx.x & 63;
    float psum[8];
#pragma unroll
    for (int j = 0; j < 8; ++j) psum[j] = 0.f;

    for (int r = 0; r < 8; ++r) {
        const int row = blockIdx.x * 128 + wave * 8 + r;
        const size_t base = (size_t)row * K_ + lane;
        float v[8];
#pragma unroll
        for (int j = 0; j < 8; ++j) v[j] = P[base + j * 64];

        float s = 0.f;
#pragma unroll
        for (int j = 0; j < 8; ++j) s += v[j];
        for (int off = 32; off > 0; off >>= 1) s += __shfl_xor(s, off);

        float theta = (s - 1.f) * (1.f / 512.f);
        int cnt = K_;
        for (int it = 0; it < K_; ++it) {
            float ls = 0.f; int lc = 0;
#pragma unroll
            for (int j = 0; j < 8; ++j)
                if (v[j] > theta) { ls += v[j]; ++lc; }
            for (int off = 32; off > 0; off >>= 1) {
                ls += __shfl_xor(ls, off);
                lc += __shfl_xor(lc, off);
            }
            if (lc == cnt) break;
            theta = (ls - 1.f) / (float)lc;
            cnt = lc;
        }
#pragma unroll
        for (int j = 0; j < 8; ++j) {
            const float o = fmaxf(v[j] - theta, 0.f);
            P[base + j * 64] = o;
            Ph[base + j * 64] = rne16(o);
            psum[j] += o;
        }
    }
#pragma unroll
    for (int j = 0; j < 8; ++j) ps[wave][lane + j * 64] = psum[j];
    __syncthreads();
    for (int c = threadIdx.x; c < 512; c += 1024) {
        float s = 0.f;
#pragma unroll
        for (int wv = 0; wv < 16; ++wv) s += ps[wv][c];
        part[(size_t)blockIdx.x * K_ + c] = s;
    }
}

// part[256][512] -> part2[16][512]
__global__ __launch_bounds__(512)
void part_reduce(const float* __restrict__ part, float* __restrict__ part2)
{
    const int t = threadIdx.x, b = blockIdx.x;
    float s = 0.f;
    for (int r = 0; r < 16; ++r) s += part[(size_t)(b * 16 + r) * K_ + t];
    part2[(size_t)b * K_ + t] = s;
}

// ---------------- finalize: scalars only -------------------------------------
#define BLOCK_REDUCE_512(val, result) \
    red[t] = (val); __syncthreads(); \
    for (int s_ = 256; s_ > 0; s_ >>= 1) { if (t < s_) red[t] += red[t + s_]; __syncthreads(); } \
    result = red[0]; __syncthreads();

__global__ __launch_bounds__(512)
void finalize_kernel(const float* __restrict__ part2, const float* __restrict__ divPart,
                     const float* __restrict__ lossPart, float* __restrict__ out_scal)
{
    __shared__ float red[512];
    const int t = threadIdx.x;

    float praw = 0.f;
    for (int b = 0; b < 16; ++b) praw += part2[b * K_ + t];
    const float pm = praw * (1.f / 32768.f);

    const float pj = fminf(fmaxf(pm, 1e-10f), 1.0f);
    float sp; BLOCK_REDUCE_512(pj, sp);
    const float pjn = pj / sp;
    float Hbits; BLOCK_REDUCE_512(-pjn * logf(pjn) / 0.69314718056f, Hbits);

    float spm; BLOCK_REDUCE_512(pm, spm);
    const float s2 = spm + 1e-5f;
    const float pmn = pm / s2;
    float ereg; BLOCK_REDUCE_512(-pmn * logf(pmn + 1e-5f), ereg);

    float dv = (t < 256) ? divPart[t] : 0.f;
    float divs; BLOCK_REDUCE_512(dv, divs);
    const float divloss = divs * (1.f / 262144.f);

    float lp = lossPart[t];
    float prim; BLOCK_REDUCE_512(lp, prim);
    prim *= 1.f / 8388608.f;

    if (t == 0) {
        out_scal[0] = prim + 0.5f * ereg + 0.5f * divloss;
        out_scal[1] = exp2f(Hbits);
    }
}

// ---------------- launch -----------------------------------------------------
extern "C" void kernel_launch(void* const* d_in, const int* in_sizes, int n_in,
                              void* d_out, int out_size, void* d_ws, size_t ws_size,
                              hipStream_t stream)
{
    const float* inputs = (const float*)d_in[0];
    const float* gamma  = (const float*)d_in[1];
    const float* beta   = (const float*)d_in[2];
    const float* C      = (const float*)d_in[3];
    const float* d_w    = (const float*)d_in[4];
    const float* d_b    = (const float*)d_in[5];

    float* out = (float*)d_out;
    float* Z = out;
    float* P = out + (size_t)M_ * D_;
    float* out_scal = P + (size_t)M_ * K_;

    float* w = (float*)d_ws;
    float* Sp   = w;     w += 4 * 65536;
    float* Tp   = w;     w += 4 * 65536;
    float* XpA  = w;     w += 4 * 65536;
    float* XpB  = w;     w += 4 * 65536;
    float* Up   = w;     w += 4 * 131072;
    float* Ap   = w;     w += 4 * 262144;
    float* Gp   = w;     w += 4 * 262144;
    float* Ct   = w;     w += 131072;
    float* cn2  = w;     w += 512;
    float* rowAbs = w;   w += 256;
    float* zn2  = w;     w += M_;
    float* part = w;     w += 256 * K_;
    float* part2 = w;    w += 16 * K_;
    float* lossPart = w; w += 512;
    float* divPart  = w; w += 256;
    float* PV   = w;     w += M_ * 4;
    float* PB   = w;     w += M_ * 4;
    int* PI     = (int*)w; w += M_ * 4;
    int* rlist  = (int*)w; w += M_;
    int* rcount = (int*)w; w += 16;
    int* assign = (int*)w; w += M_;
    unsigned short* Zh  = (unsigned short*)w; w += M_ * D_ / 2;
    unsigned short* Zl  = (unsigned short*)w; w += M_ * D_ / 2;
    unsigned short* Cth = (unsigned short*)w; w += (K_ * D_) / 2;
    unsigned short* Ctl = (unsigned short*)w; w += (K_ * D_) / 2;
    unsigned short* Ch  = (unsigned short*)w; w += (K_ * D_) / 2;
    unsigned short* Uth = (unsigned short*)w; w += (K_ * D_) / 2;
    unsigned short* Ph  = Zh;   // M_*K_ u16 = 32MB, aliases Zh+Zl (dead then)

    // 1. Z = LN(inputs @ d_w + d_b), zn2, Zh/Zl planes
    dense_ln_kernel<<<M_/64, 256, 0, stream>>>(inputs, d_w, d_b, gamma, beta, Z, zn2, Zh, Zl);
    // 2. prep: Ct + planes + Ch + cn2 + rcount=0
    prep_c<<<K_, 256, 0, stream>>>(C, Ct, Cth, Ctl, Ch, cn2, rcount);
    // 3. S partials = C C^T (split-K)
    sk_gemm<1, 0, 0, 0><<<dim3(4, 4, 4), 256, 0, stream>>>(Ct, Ct, Sp, 256, 256, 512, nullptr);
    // 4. NS init: rowAbs -> X1 partials (slice0 = 2cI - c^2 S, rest 0)
    rowabs_kernel<<<256, 256, 0, stream>>>(Sp, rowAbs);
    x1_init<<<256, 256, 0, stream>>>(rowAbs, Sp, XpA);
    // 5. Newton-Schulz x3 with virtual X (sum-of-partials operands)
    float* Xc = XpA; float* Xn = XpB;
    for (int it = 0; it < 3; ++it) {
        sk_gemm<0, 2, 1, 0><<<dim3(4, 4, 4), 256, 0, stream>>>(Sp, Xc, Tp, 256, 256, 256, nullptr);
        sk_gemm<0, 1, 1, 1><<<dim3(4, 4, 4), 256, 0, stream>>>(Xc, Tp, Xn, 256, 256, 256, Xc);
        float* tmp = Xc; Xc = Xn; Xn = tmp;
    }
    // 6. Ut partials (B = virtual Sinv); Ainv partials; G partials; reduces
    sk_gemm<1, 0, 1, 0><<<dim3(4, 8, 4), 256, 0, stream>>>(C, Xc, Up, 512, 256, 256, nullptr);
    sk_gemm<0, 1, 0, 0><<<dim3(8, 8, 4), 256, 0, stream>>>(Up, C, Ap, 512, 512, 256, nullptr);
    sk_gemm<1, 0, 0, 0><<<dim3(8, 8, 4), 256, 0, stream>>>(C, C, Gp, 512, 512, 256, nullptr);
    gut_reduce<<<768, 256, 0, stream>>>(Up, Uth, Gp, cn2, divPart);
    // 7. score (x3 MFMA on planes) + top-2 -> assign + repair set
    score_mfma_argmin<<<dim3(K_/128, M_/128), 256, 0, stream>>>(Zh, Zl, Cth, Ctl, cn2, zn2, PV, PB, PI);
    argmin_reduce4<<<M_/256, 256, 0, stream>>>(PV, PB, PI, assign, rlist, rcount);
    repair_gemm<<<M_/128, 256, 0, stream>>>(Z, C, cn2, zn2, rlist, rcount, assign);
    // 8. P_sol^T = Z @ Ut^T + (I - sum4(Ap))[assign,:]
    mfma_gemm<2><<<dim3(K_/128, M_/128), 256, 0, stream>>>(
        Zh, Uth, P, D_, K_, Ap, assign, nullptr, nullptr);
    // 9. simplex projection + column sums + Ph plane
    project_colsum_kernel<<<M_/128, 1024, 0, stream>>>(P, Ph, part);
    part_reduce<<<16, 512, 0, stream>>>(part, part2);
    // 10. Zq = P @ C^T (Ph x Ch planes), loss partials
    mfma_gemm<3><<<dim3(D_/128, M_/128), 256, 0, stream>>>(
        Ph, Ch, Z, K_, D_, nullptr, nullptr, Z, lossPart);
    // 11. scalars
    finalize_kernel<<<1, 512, 0, stream>>>(part2, divPart, lossPart, out_scal);

    (void)in_sizes; (void)n_in; (void)out_size; (void)ws_size;
}

// Round 13
// 387.404 us; speedup vs baseline: 1.2871x; 1.2871x over previous
//
#include <hip/hip_runtime.h>
#include <math.h>

// SCQ layer forward.
//   dense+LN f32 double-buffered -> Zh/Zl RNE-split planes.
//   score: x3-MFMA on planes + top-2; gap < TAU repaired by exact f32 GEMM
//   (PARALLEL: 4 col-stripe blocks per row group + scatter — the r12
//   stripe-looped variant serialized to 158us, reverted).
//   small chain: split-K GEMMs, virtual X (sum-of-4-partials operands);
//   NS: closed-form step 1 + 3 GEMM iterations. Ainv materialized by a tiny
//   reduce (in-epilogue partial sums cost ~200MB of gather traffic).
//   prep_c fuses Ct/planes/Ch/cn2/rcount; project+colsum+Ph fused.

#define M_ 32768
#define D_ 256
#define K_ 512
#define TAU 0.006f

typedef short bf16x8 __attribute__((ext_vector_type(8)));
typedef unsigned short u16x8 __attribute__((ext_vector_type(8)));
typedef unsigned short u16x4 __attribute__((ext_vector_type(4)));
typedef float f32x4 __attribute__((ext_vector_type(4)));

#define LSTR 56

__device__ inline void split_rne(float f, unsigned short& h, unsigned short& l)
{
    unsigned int u = __float_as_uint(f);
    unsigned int uh = u + (0x7FFFu + ((u >> 16) & 1u));
    h = (unsigned short)(uh >> 16);
    float fh = __uint_as_float(((unsigned int)h) << 16);
    float r = f - fh;
    l = (unsigned short)(__float_as_uint(r) >> 16);
}

__device__ inline unsigned short rne16(float f)
{
    unsigned int u = __float_as_uint(f);
    u += 0x7FFFu + ((u >> 16) & 1u);
    return (unsigned short)(u >> 16);
}

// ---- MFMA GEMM (single bf16): Out = A @ Bt^T, operands as u16 planes -------
// EPI: 2 = +Ainv[assign[row], col];  3 = Zq + loss partials
template<int EPI>
__global__ __launch_bounds__(256)
void mfma_gemm(const unsigned short* __restrict__ Ah,
               const unsigned short* __restrict__ Bh,
               float* __restrict__ Out, int Kd, int N,
               const float* __restrict__ AinvM, const int* __restrict__ assign,
               const float* Zref, float* __restrict__ lossPart)
{
    __shared__ unsigned short sA[128*LSTR];
    __shared__ unsigned short sB[128*LSTR];
    __shared__ float red[256];
    const int tid = threadIdx.x;
    const int m0 = blockIdx.y * 128, n0 = blockIdx.x * 128;
    const int w = tid >> 6, lane = tid & 63;
    const int wr = (w & 1) * 64, wc = (w >> 1) * 64;
    const int cg = lane >> 4, cr = lane & 15;

    f32x4 acc[4][4];
    const f32x4 z4 = {0.f, 0.f, 0.f, 0.f};
#pragma unroll
    for (int i = 0; i < 4; ++i)
#pragma unroll
        for (int j = 0; j < 4; ++j) acc[i][j] = z4;

    const int sr = tid >> 1;
    const int sk = (tid & 1) * 16;
    const int soff = sr * LSTR + sk;
    const unsigned short* Agh = Ah + (size_t)(m0 + sr) * Kd + sk;
    const unsigned short* Bgh = Bh + (size_t)(n0 + sr) * Kd + sk;

    for (int kb = 0; kb < Kd; kb += 32) {
        *(u16x8*)&sA[soff]     = *(const u16x8*)(Agh + kb);
        *(u16x8*)&sA[soff + 8] = *(const u16x8*)(Agh + kb + 8);
        *(u16x8*)&sB[soff]     = *(const u16x8*)(Bgh + kb);
        *(u16x8*)&sB[soff + 8] = *(const u16x8*)(Bgh + kb + 8);
        __syncthreads();
        bf16x8 ah[4], bh[4];
#pragma unroll
        for (int f = 0; f < 4; ++f) {
            ah[f] = *(const bf16x8*)&sA[(wr + f*16 + cr) * LSTR + cg*8];
            bh[f] = *(const bf16x8*)&sB[(wc + f*16 + cr) * LSTR + cg*8];
        }
#pragma unroll
        for (int i = 0; i < 4; ++i)
#pragma unroll
            for (int j = 0; j < 4; ++j)
                acc[i][j] = __builtin_amdgcn_mfma_f32_16x16x32_bf16(ah[i], bh[j], acc[i][j], 0, 0, 0);
        __syncthreads();
    }

    if (EPI == 2) {
#pragma unroll
        for (int i = 0; i < 4; ++i) {
#pragma unroll
            for (int q = 0; q < 4; ++q) {
                const int row = m0 + wr + i*16 + cg*4 + q;
                const int am = assign[row];
                const float* Arow = AinvM + (size_t)am * K_ + n0 + wc;
#pragma unroll
                for (int j = 0; j < 4; ++j)
                    Out[(size_t)row * N + n0 + wc + j*16 + cr] =
                        acc[i][j][q] + Arow[j*16 + cr];
            }
        }
    } else {
        float lsum = 0.f;
#pragma unroll
        for (int i = 0; i < 4; ++i) {
#pragma unroll
            for (int q = 0; q < 4; ++q) {
                const int row = m0 + wr + i*16 + cg*4 + q;
#pragma unroll
                for (int j = 0; j < 4; ++j) {
                    const int col = n0 + wc + j*16 + cr;
                    const float v = acc[i][j][q];
                    const float zv = Zref[(size_t)row * N + col];
                    const float d = v - zv;
                    lsum += d * d;
                    Out[(size_t)row * N + col] = v;
                }
            }
        }
        red[tid] = lsum;
        __syncthreads();
        for (int s = 128; s > 0; s >>= 1) {
            if (tid < s) red[tid] += red[tid + s];
            __syncthreads();
        }
        if (tid == 0) lossPart[blockIdx.y * gridDim.x + blockIdx.x] = red[0];
    }
}

// -------- score: x3 MFMA on pre-split planes + per-row per-stripe top-2 -----
__global__ __launch_bounds__(256)
void score_mfma_argmin(const unsigned short* __restrict__ Zh, const unsigned short* __restrict__ Zl,
                       const unsigned short* __restrict__ Bth, const unsigned short* __restrict__ Btl,
                       const float* __restrict__ cn2, const float* __restrict__ zn2,
                       float* __restrict__ PV, float* __restrict__ PB,
                       int* __restrict__ PI)
{
    __shared__ unsigned short sAh[128*LSTR], sAl[128*LSTR];
    __shared__ unsigned short sBh[128*LSTR], sBl[128*LSTR];
    __shared__ float l1v[128][2], l2v[128][2];
    __shared__ int   liv[128][2];
    const int tid = threadIdx.x;
    const int m0 = blockIdx.y * 128, n0 = blockIdx.x * 128;
    const int w = tid >> 6, lane = tid & 63;
    const int wr = (w & 1) * 64, wc = (w >> 1) * 64;
    const int cg = lane >> 4, cr = lane & 15;

    f32x4 acc[4][4];
    const f32x4 z4 = {0.f, 0.f, 0.f, 0.f};
#pragma unroll
    for (int i = 0; i < 4; ++i)
#pragma unroll
        for (int j = 0; j < 4; ++j) acc[i][j] = z4;

    const int sr = tid >> 1;
    const int sk = (tid & 1) * 16;
    const int soff = sr * LSTR + sk;
    const unsigned short* Ah = Zh  + (size_t)(m0 + sr) * D_ + sk;
    const unsigned short* Al = Zl  + (size_t)(m0 + sr) * D_ + sk;
    const unsigned short* Bh = Bth + (size_t)(n0 + sr) * D_ + sk;
    const unsigned short* Bl = Btl + (size_t)(n0 + sr) * D_ + sk;

    for (int kb = 0; kb < D_; kb += 32) {
        *(u16x8*)&sAh[soff]     = *(const u16x8*)(Ah + kb);
        *(u16x8*)&sAh[soff + 8] = *(const u16x8*)(Ah + kb + 8);
        *(u16x8*)&sAl[soff]     = *(const u16x8*)(Al + kb);
        *(u16x8*)&sAl[soff + 8] = *(const u16x8*)(Al + kb + 8);
        *(u16x8*)&sBh[soff]     = *(const u16x8*)(Bh + kb);
        *(u16x8*)&sBh[soff + 8] = *(const u16x8*)(Bh + kb + 8);
        *(u16x8*)&sBl[soff]     = *(const u16x8*)(Bl + kb);
        *(u16x8*)&sBl[soff + 8] = *(const u16x8*)(Bl + kb + 8);
        __syncthreads();
        bf16x8 ah[4], al[4], bh[4], bl[4];
#pragma unroll
        for (int f = 0; f < 4; ++f) {
            const int ao = (wr + f*16 + cr) * LSTR + cg*8;
            ah[f] = *(const bf16x8*)&sAh[ao];
            al[f] = *(const bf16x8*)&sAl[ao];
            const int bo = (wc + f*16 + cr) * LSTR + cg*8;
            bh[f] = *(const bf16x8*)&sBh[bo];
            bl[f] = *(const bf16x8*)&sBl[bo];
        }
#pragma unroll
        for (int i = 0; i < 4; ++i)
#pragma unroll
            for (int j = 0; j < 4; ++j) {
                acc[i][j] = __builtin_amdgcn_mfma_f32_16x16x32_bf16(ah[i], bh[j], acc[i][j], 0, 0, 0);
                acc[i][j] = __builtin_amdgcn_mfma_f32_16x16x32_bf16(al[i], bh[j], acc[i][j], 0, 0, 0);
                acc[i][j] = __builtin_amdgcn_mfma_f32_16x16x32_bf16(ah[i], bl[j], acc[i][j], 0, 0, 0);
            }
        __syncthreads();
    }

    const int half = wc >> 6;
#pragma unroll
    for (int i = 0; i < 4; ++i) {
#pragma unroll
        for (int q = 0; q < 4; ++q) {
            const int rl = wr + i*16 + cg*4 + q;
            const float zr = zn2[m0 + rl];
            float b1 = 3.4e38f, b2 = 3.4e38f; int i1 = 0x7fffffff;
#pragma unroll
            for (int j = 0; j < 4; ++j) {
                const int col = n0 + wc + j*16 + cr;
                const float d = (zr + cn2[col]) - 2.0f * acc[i][j][q];
                if (d < b1 || (d == b1 && col < i1)) { b2 = b1; b1 = d; i1 = col; }
                else if (d < b2) b2 = d;
            }
#pragma unroll
            for (int off = 1; off < 16; off <<= 1) {
                const float o1 = __shfl_xor(b1, off);
                const int   oi = __shfl_xor(i1, off);
                const float o2 = __shfl_xor(b2, off);
                if (o1 < b1 || (o1 == b1 && oi < i1)) { b2 = fminf(b1, o2); b1 = o1; i1 = oi; }
                else { b2 = fminf(o1, b2); }
            }
            if (cr == 0) { l1v[rl][half] = b1; l2v[rl][half] = b2; liv[rl][half] = i1; }
        }
    }
    __syncthreads();
    if (tid < 128) {
        const float a1 = l1v[tid][0], a2 = l2v[tid][0]; const int ai = liv[tid][0];
        const float c1 = l1v[tid][1], c2 = l2v[tid][1]; const int ci = liv[tid][1];
        float b1, b2; int bi;
        if (c1 < a1 || (c1 == a1 && ci < ai)) { b1 = c1; bi = ci; b2 = fminf(a1, c2); }
        else { b1 = a1; bi = ai; b2 = fminf(c1, a2); }
        const size_t o = (size_t)(m0 + tid) * 4 + blockIdx.x;
        PV[o] = b1; PB[o] = b2; PI[o] = bi;
    }
}

__global__ void argmin_reduce4(const float* __restrict__ PV, const float* __restrict__ PB,
                               const int* __restrict__ PI, int* __restrict__ assign,
                               int* __restrict__ rlist, int* __restrict__ rcount)
{
    const int m = blockIdx.x * 256 + threadIdx.x;
    float b1 = PV[(size_t)m*4], b2 = PB[(size_t)m*4]; int i1 = PI[(size_t)m*4];
#pragma unroll
    for (int s = 1; s < 4; ++s) {
        const float o1 = PV[(size_t)m*4+s], o2 = PB[(size_t)m*4+s];
        const int oi = PI[(size_t)m*4+s];
        if (o1 < b1 || (o1 == b1 && oi < i1)) { b2 = fminf(b1, o2); b1 = o1; i1 = oi; }
        else { b2 = fminf(o1, b2); }
    }
    assign[m] = i1;
    if (b2 - b1 < TAU) { const int p = atomicAdd(rcount, 1); rlist[p] = m; }
}

// -------- compacted f32 rescoring GEMM over ambiguous rows (parallel) -------
__global__ __launch_bounds__(256)
void repair_gemm(const float* __restrict__ Z, const float* __restrict__ B,
                 const float* __restrict__ cn2, const float* __restrict__ zn2,
                 const int* __restrict__ rlist, const int* __restrict__ rcount,
                 float* __restrict__ PV, int* __restrict__ PI)
{
    const int n = rcount[0];
    const int m0 = blockIdx.y * 128;
    if (m0 >= n) return;
    __shared__ float As[16][132];
    __shared__ float Bs[16][128];
    __shared__ int rows_s[128];
    const int tid = threadIdx.x;
    const int tx = tid & 15, ty = tid >> 4;
    const int n0 = blockIdx.x * 128;

    if (tid < 128) rows_s[tid] = (m0 + tid < n) ? rlist[m0 + tid] : rlist[0];
    __syncthreads();

    float acc[8][8];
#pragma unroll
    for (int i = 0; i < 8; ++i)
#pragma unroll
        for (int j = 0; j < 8; ++j) acc[i][j] = 0.f;

    const int ar = tid >> 1, ac = (tid & 1) * 8;
    const int br = tid >> 4, bc = (tid & 15) * 8;
    const float* Ap = Z + (size_t)rows_s[ar] * D_ + ac;
    const float* Bp = B + (size_t)br * K_ + n0 + bc;

    for (int kb = 0; kb < D_; kb += 16) {
        float4 a0 = *(const float4*)(Ap + kb);
        float4 a1 = *(const float4*)(Ap + kb + 4);
        float4 b0 = *(const float4*)(Bp + (size_t)kb * K_);
        float4 b1 = *(const float4*)(Bp + (size_t)kb * K_ + 4);
        As[ac+0][ar] = a0.x; As[ac+1][ar] = a0.y; As[ac+2][ar] = a0.z; As[ac+3][ar] = a0.w;
        As[ac+4][ar] = a1.x; As[ac+5][ar] = a1.y; As[ac+6][ar] = a1.z; As[ac+7][ar] = a1.w;
        *(float4*)&Bs[br][bc]     = b0;
        *(float4*)&Bs[br][bc + 4] = b1;
        __syncthreads();
#pragma unroll
        for (int kk = 0; kk < 16; ++kk) {
            float4 av0 = *(const float4*)&As[kk][ty*4];
            float4 av1 = *(const float4*)&As[kk][64 + ty*4];
            float4 bv0 = *(const float4*)&Bs[kk][tx*4];
            float4 bv1 = *(const float4*)&Bs[kk][64 + tx*4];
            float a_[8] = {av0.x, av0.y, av0.z, av0.w, av1.x, av1.y, av1.z, av1.w};
            float b_[8] = {bv0.x, bv0.y, bv0.z, bv0.w, bv1.x, bv1.y, bv1.z, bv1.w};
#pragma unroll
            for (int i = 0; i < 8; ++i)
#pragma unroll
                for (int j = 0; j < 8; ++j)
                    acc[i][j] = fmaf(a_[i], b_[j], acc[i][j]);
        }
        __syncthreads();
    }

#pragma unroll
    for (int hi = 0; hi < 2; ++hi) {
#pragma unroll
        for (int i = 0; i < 4; ++i) {
            const int rl = hi*64 + ty*4 + i;
            if (m0 + rl >= n) continue;
            const float zr = zn2[rows_s[rl]];
            float best = 3.4e38f; int bi = 0x7fffffff;
#pragma unroll
            for (int hj = 0; hj < 2; ++hj) {
#pragma unroll
                for (int j = 0; j < 4; ++j) {
                    const int col = n0 + hj*64 + tx*4 + j;
                    const float t1 = zr + cn2[col];
                    const float d  = t1 - 2.0f * acc[hi*4+i][hj*4+j];
                    if (d < best) { best = d; bi = col; }
                }
            }
#pragma unroll
            for (int off = 1; off < 16; off <<= 1) {
                const float ov = __shfl_xor(best, off);
                const int   oi = __shfl_xor(bi, off);
                if (ov < best || (ov == best && oi < bi)) { best = ov; bi = oi; }
            }
            if (tx == 0) {
                PV[(size_t)(m0 + rl) * 4 + blockIdx.x] = best;
                PI[(size_t)(m0 + rl) * 4 + blockIdx.x] = bi;
            }
        }
    }
}

__global__ void repair_scatter(const float* __restrict__ PV, const int* __restrict__ PI,
                               const int* __restrict__ rlist, const int* __restrict__ rcount,
                               int* __restrict__ assign)
{
    const int r = blockIdx.x * 256 + threadIdx.x;
    if (r >= rcount[0]) return;
    float best = PV[(size_t)r * 4]; int bi = PI[(size_t)r * 4];
#pragma unroll
    for (int nb = 1; nb < 4; ++nb) {
        const float v = PV[(size_t)r * 4 + nb]; const int ix = PI[(size_t)r * 4 + nb];
        if (v < best || (v == best && ix < bi)) { best = v; bi = ix; }
    }
    assign[rlist[r]] = bi;
}

// ------- fused dense (64x256, double-buffered) + LayerNorm + Z planes -------
__global__ __launch_bounds__(256)
void dense_ln_kernel(const float* __restrict__ A, const float* __restrict__ Bw,
                     const float* __restrict__ bias, const float* __restrict__ gamma,
                     const float* __restrict__ beta, float* __restrict__ Z,
                     float* __restrict__ zn2,
                     unsigned short* __restrict__ Zh, unsigned short* __restrict__ Zl)
{
    __shared__ float As[2][16][68];
    __shared__ float Bs[2][16][260];
    __shared__ float rred[64][17];
    __shared__ float rstat[64];
    const int tid = threadIdx.x, tx = tid & 15, ty = tid >> 4;
    const int m0 = blockIdx.x * 64;
    float acc[4][16];
#pragma unroll
    for (int i = 0; i < 4; ++i)
#pragma unroll
        for (int j = 0; j < 16; ++j) acc[i][j] = 0.f;

    const int ar = tid >> 2, ac = (tid & 3) * 4;
    const int br = tid >> 4, bc = (tid & 15) * 16;

#define DL_STAGE(buf, kb) { \
    float4 a = *(const float4*)(A + (size_t)(m0 + ar) * 256 + (kb) + ac); \
    As[buf][ac+0][ar] = a.x; As[buf][ac+1][ar] = a.y; \
    As[buf][ac+2][ar] = a.z; As[buf][ac+3][ar] = a.w; \
    _Pragma("unroll") \
    for (int q = 0; q < 4; ++q) \
        *(float4*)&Bs[buf][br][bc + q*4] = \
            *(const float4*)(Bw + (size_t)((kb) + br) * 256 + bc + q*4); }

    DL_STAGE(0, 0)
    __syncthreads();
    for (int t16 = 0; t16 < 16; ++t16) {
        const int cur = t16 & 1;
        if (t16 < 15) DL_STAGE(cur ^ 1, (t16 + 1) * 16)
#pragma unroll
        for (int kk = 0; kk < 16; ++kk) {
            float4 a4 = *(const float4*)&As[cur][kk][ty*4];
            float av[4] = {a4.x, a4.y, a4.z, a4.w};
            float bv[16];
#pragma unroll
            for (int q = 0; q < 4; ++q) {
                float4 b4 = *(const float4*)&Bs[cur][kk][q*64 + tx*4];
                bv[q*4+0] = b4.x; bv[q*4+1] = b4.y; bv[q*4+2] = b4.z; bv[q*4+3] = b4.w;
            }
#pragma unroll
            for (int i = 0; i < 4; ++i)
#pragma unroll
                for (int j = 0; j < 16; ++j)
                    acc[i][j] = fmaf(av[i], bv[j], acc[i][j]);
        }
        __syncthreads();
    }
#undef DL_STAGE

    float bcol[16];
#pragma unroll
    for (int q = 0; q < 4; ++q) {
        float4 b4 = *(const float4*)(bias + q*64 + tx*4);
        bcol[q*4+0] = b4.x; bcol[q*4+1] = b4.y; bcol[q*4+2] = b4.z; bcol[q*4+3] = b4.w;
    }
#pragma unroll
    for (int i = 0; i < 4; ++i)
#pragma unroll
        for (int j = 0; j < 16; ++j) acc[i][j] += bcol[j];

#pragma unroll
    for (int i = 0; i < 4; ++i) {
        float s = 0.f;
#pragma unroll
        for (int j = 0; j < 16; ++j) s += acc[i][j];
        rred[ty*4+i][tx] = s;
    }
    __syncthreads();
    if (tid < 64) {
        float s = 0.f;
#pragma unroll
        for (int t = 0; t < 16; ++t) s += rred[tid][t];
        rstat[tid] = s * (1.f / 256.f);
    }
    __syncthreads();
    float mean_[4];
#pragma unroll
    for (int i = 0; i < 4; ++i) mean_[i] = rstat[ty*4+i];

#pragma unroll
    for (int i = 0; i < 4; ++i) {
        float s = 0.f;
#pragma unroll
        for (int j = 0; j < 16; ++j) { float d = acc[i][j] - mean_[i]; s += d * d; }
        rred[ty*4+i][tx] = s;
    }
    __syncthreads();
    if (tid < 64) {
        float s = 0.f;
#pragma unroll
        for (int t = 0; t < 16; ++t) s += rred[tid][t];
        rstat[tid] = s * (1.f / 256.f);
    }
    __syncthreads();
    float rstd_[4];
#pragma unroll
    for (int i = 0; i < 4; ++i) rstd_[i] = sqrtf(rstat[ty*4+i] + 1e-5f);

    float gam[16], bet[16];
#pragma unroll
    for (int q = 0; q < 4; ++q) {
        float4 g4 = *(const float4*)(gamma + q*64 + tx*4);
        float4 e4 = *(const float4*)(beta  + q*64 + tx*4);
        gam[q*4+0] = g4.x; gam[q*4+1] = g4.y; gam[q*4+2] = g4.z; gam[q*4+3] = g4.w;
        bet[q*4+0] = e4.x; bet[q*4+1] = e4.y; bet[q*4+2] = e4.z; bet[q*4+3] = e4.w;
    }
#pragma unroll
    for (int i = 0; i < 4; ++i)
#pragma unroll
        for (int j = 0; j < 16; ++j) {
            const float d = acc[i][j] - mean_[i];
            acc[i][j] = gam[j] * (d / rstd_[i]) + bet[j];
        }

#pragma unroll
    for (int i = 0; i < 4; ++i) {
        float s = 0.f;
#pragma unroll
        for (int j = 0; j < 16; ++j) s += acc[i][j] * acc[i][j];
        rred[ty*4+i][tx] = s;
    }
    __syncthreads();
    if (tid < 64) {
        float s = 0.f;
#pragma unroll
        for (int t = 0; t < 16; ++t) s += rred[tid][t];
        zn2[m0 + tid] = s;
    }

#pragma unroll
    for (int i = 0; i < 4; ++i) {
        const int row = m0 + ty*4 + i;
#pragma unroll
        for (int q = 0; q < 4; ++q) {
            float4 v;
            v.x = acc[i][q*4+0]; v.y = acc[i][q*4+1];
            v.z = acc[i][q*4+2]; v.w = acc[i][q*4+3];
            const size_t pos = (size_t)row * 256 + q*64 + tx*4;
            *(float4*)(Z + pos) = v;
            unsigned short h[4], l[4];
            split_rne(v.x, h[0], l[0]); split_rne(v.y, h[1], l[1]);
            split_rne(v.z, h[2], l[2]); split_rne(v.w, h[3], l[3]);
            *(u16x4*)(Zh + pos) = *(u16x4*)h;
            *(u16x4*)(Zl + pos) = *(u16x4*)l;
        }
    }
}

// ---------------- split-K small GEMM: 64x64 tiles, grid.z = 4 slices --------
template<int TRA, int ASUM, int BSUM, int OEPI>
__global__ __launch_bounds__(256)
void sk_gemm(const float* __restrict__ A, const float* __restrict__ B,
             float* __restrict__ Out, int M, int N, int Kd,
             const float* __restrict__ Xprev)
{
    __shared__ float As[16][68];
    __shared__ float Bs[16][68];
    const int tid = threadIdx.x;
    const int tx = tid & 15, ty = tid >> 4;
    const int n0 = blockIdx.x * 64, m0 = blockIdx.y * 64;
    const int kw = Kd >> 2;
    const int kb0 = blockIdx.z * kw;
    const size_t aP = (size_t)M * Kd;
    const size_t bP = (size_t)Kd * N;
    float acc[4][4];
#pragma unroll
    for (int i = 0; i < 4; ++i)
#pragma unroll
        for (int j = 0; j < 4; ++j) acc[i][j] = 0.f;

    for (int kb = kb0; kb < kb0 + kw; kb += 16) {
        if (TRA == 0) {
            const int ar2 = tid >> 2, ac2 = (tid & 3) * 4;
            const size_t off = (size_t)(m0 + ar2) * Kd + kb + ac2;
            float4 a;
            if (ASUM) {
                float4 a0 = *(const float4*)(A + off);
                float4 a1 = *(const float4*)(A + aP + off);
                float4 a2 = *(const float4*)(A + 2*aP + off);
                float4 a3 = *(const float4*)(A + 3*aP + off);
                a.x = a0.x + a1.x + a2.x + a3.x;
                a.y = a0.y + a1.y + a2.y + a3.y;
                a.z = a0.z + a1.z + a2.z + a3.z;
                a.w = a0.w + a1.w + a2.w + a3.w;
                if (ASUM == 2) {
                    const int row = m0 + ar2, colb = kb + ac2;
                    if (row == colb)     a.x += 1.f;
                    if (row == colb + 1) a.y += 1.f;
                    if (row == colb + 2) a.z += 1.f;
                    if (row == colb + 3) a.w += 1.f;
                }
            } else {
                a = *(const float4*)(A + off);
            }
            As[ac2+0][ar2] = a.x; As[ac2+1][ar2] = a.y;
            As[ac2+2][ar2] = a.z; As[ac2+3][ar2] = a.w;
        } else {
            const int ar2 = tid >> 4, ac2 = (tid & 15) * 4;
            float4 a = *(const float4*)(A + (size_t)(kb + ar2) * M + m0 + ac2);
            *(float4*)&As[ar2][ac2] = a;
        }
        {
            const int br2 = tid >> 4, bc2 = (tid & 15) * 4;
            const size_t off = (size_t)(kb + br2) * N + n0 + bc2;
            float4 b;
            if (BSUM) {
                float4 b0 = *(const float4*)(B + off);
                float4 b1 = *(const float4*)(B + bP + off);
                float4 b2 = *(const float4*)(B + 2*bP + off);
                float4 b3 = *(const float4*)(B + 3*bP + off);
                b.x = b0.x + b1.x + b2.x + b3.x;
                b.y = b0.y + b1.y + b2.y + b3.y;
                b.z = b0.z + b1.z + b2.z + b3.z;
                b.w = b0.w + b1.w + b2.w + b3.w;
            } else {
                b = *(const float4*)(B + off);
            }
            *(float4*)&Bs[br2][bc2] = b;
        }
        __syncthreads();
#pragma unroll
        for (int kk = 0; kk < 16; ++kk) {
            float4 a4 = *(const float4*)&As[kk][ty*4];
            float4 b4 = *(const float4*)&Bs[kk][tx*4];
            float a_[4] = {a4.x, a4.y, a4.z, a4.w};
            float b_[4] = {b4.x, b4.y, b4.z, b4.w};
#pragma unroll
            for (int i = 0; i < 4; ++i)
#pragma unroll
                for (int j = 0; j < 4; ++j)
                    acc[i][j] = fmaf(a_[i], b_[j], acc[i][j]);
        }
        __syncthreads();
    }
    const size_t MN = (size_t)M * N;
    float* Op = Out + (size_t)blockIdx.z * MN;
#pragma unroll
    for (int i = 0; i < 4; ++i)
#pragma unroll
        for (int j = 0; j < 4; ++j) {
            const size_t idx = (size_t)(m0 + ty*4 + i) * N + n0 + tx*4 + j;
            if (OEPI == 0) {
                Op[idx] = acc[i][j];
            } else {
                float base = 0.f;
                if (blockIdx.z == 0)
                    base = 2.f * (Xprev[idx] + Xprev[MN + idx] +
                                  Xprev[2*MN + idx] + Xprev[3*MN + idx]);
                Op[idx] = base - acc[i][j];
            }
        }
}

// --------- prep_c: Ct + RNE planes + Ch + cn2 + rcount zero -----------------
__global__ __launch_bounds__(256)
void prep_c(const float* __restrict__ C, float* __restrict__ Ct,
            unsigned short* __restrict__ Cth, unsigned short* __restrict__ Ctl,
            unsigned short* __restrict__ Ch, float* __restrict__ cn2,
            int* __restrict__ rcount)
{
    __shared__ float red[256];
    const int k = blockIdx.x, t = threadIdx.x;
    const float v = C[(size_t)t * K_ + k];
    Ct[k * 256 + t] = v;
    unsigned short h, l;
    split_rne(v, h, l);
    Cth[k * 256 + t] = h;
    Ctl[k * 256 + t] = l;
    Ch[(size_t)t * K_ + k] = h;
    red[t] = v * v;
    __syncthreads();
    for (int s = 128; s > 0; s >>= 1) { if (t < s) red[t] += red[t + s]; __syncthreads(); }
    if (t == 0) {
        cn2[k] = red[0];
        if (k == 0) rcount[0] = 0;
    }
}

__global__ void rowabs_kernel(const float* __restrict__ Sp, float* __restrict__ rowAbs)
{
    __shared__ float red[256];
    const int r = blockIdx.x, t = threadIdx.x;
    const int idx = r * 256 + t;
    float v = Sp[idx] + Sp[65536 + idx] + Sp[131072 + idx] + Sp[196608 + idx];
    if (r == t) v += 1.f;
    red[t] = fabsf(v); __syncthreads();
    for (int s = 128; s > 0; s >>= 1) {
        if (t < s) red[t] += red[t + s];
        __syncthreads();
    }
    if (t == 0) rowAbs[r] = red[0];
}

// X1 = 2cI - c^2 S written as 4 partial slices (slice0 = X1, rest 0)
__global__ void x1_init(const float* __restrict__ rowAbs, const float* __restrict__ Sp,
                        float* __restrict__ Xp)
{
    __shared__ float red[256];
    const int t = threadIdx.x;
    red[t] = rowAbs[t]; __syncthreads();
    for (int s = 128; s > 0; s >>= 1) {
        if (t < s) red[t] = fmaxf(red[t], red[t + s]);
        __syncthreads();
    }
    const float c = 2.f / (1.f + red[0]);
    const int idx = blockIdx.x * 256 + t;
    const int i = idx >> 8, j = idx & 255;
    float s4 = Sp[idx] + Sp[65536 + idx] + Sp[131072 + idx] + Sp[196608 + idx];
    if (i == j) s4 += 1.f;
    const float tt = c * s4;
    const float xp = c * tt;
    Xp[idx] = ((i == j) ? 2.f * c : 0.f) - xp;
    Xp[65536 + idx]  = 0.f;
    Xp[131072 + idx] = 0.f;
    Xp[196608 + idx] = 0.f;
}

// Ainv = I - sum4(Ap)
__global__ void ainv_reduce(const float* __restrict__ Ap, float* __restrict__ Ainv)
{
    const int idx = blockIdx.x * 256 + threadIdx.x;
    const int i = idx >> 9, j = idx & 511;
    const float s = Ap[idx] + Ap[262144 + idx] + Ap[524288 + idx] + Ap[786432 + idx];
    Ainv[idx] = ((i == j) ? 1.f : 0.f) - s;
}

// -------- merged: Uth reduce (blocks 0..511) + diversity (blocks 512..767) --
__global__ __launch_bounds__(256)
void gut_reduce(const float* __restrict__ Up, unsigned short* __restrict__ Uth,
                const float* __restrict__ Gp, const float* __restrict__ cn2,
                float* __restrict__ divPart)
{
    __shared__ float red[256];
    __shared__ float rsn[512];
    const int b = blockIdx.x, t = threadIdx.x;
    if (b < 512) {
        const int idx = b * 256 + t;
        Uth[idx] = rne16(Up[idx] + Up[131072 + idx] + Up[262144 + idx] + Up[393216 + idx]);
        return;
    }
    const int gb = b - 512;
    rsn[t]       = 1.f / sqrtf(fmaxf(cn2[t], 1e-12f));
    rsn[t + 256] = 1.f / sqrtf(fmaxf(cn2[t + 256], 1e-12f));
    __syncthreads();
    float dsum = 0.f;
#pragma unroll
    for (int e = 0; e < 4; ++e) {
        const int idx = gb * 1024 + e * 256 + t;
        const int i = idx >> 9, j = idx & 511;
        const float g = Gp[idx] + Gp[262144 + idx] + Gp[524288 + idx] + Gp[786432 + idx];
        if (i != j) dsum += fmaxf(g * rsn[i] * rsn[j], 0.f);
    }
    red[t] = dsum; __syncthreads();
    for (int s = 128; s > 0; s >>= 1) {
        if (t < s) red[t] += red[t + s];
        __syncthreads();
    }
    if (t == 0) divPart[gb] = red[0];
}

// ------- simplex projection (Michelot) fused with column sums + Ph plane ----
__global__ __launch_bounds__(1024)
void project_colsum_kernel(float* P, unsigned short* __restrict__ Ph,
                           float* __restrict__ part)
{
    __shared__ float ps[16][512];
    const int wave = threadIdx.x >> 6;
    const int lane = threadIdx.x & 63;
    float psum[8];
#pragma unroll
    for (int j = 0; j < 8; ++j) psum[j] = 0.f;

    for (int r = 0; r < 8; ++r) {
        const int row = blockIdx.x * 128 + wave * 8 + r;
        const size_t base = (size_t)row * K_ + lane;
        float v[8];
#pragma unroll
        for (int j = 0; j < 8; ++j) v[j] = P[base + j * 64];

        float s = 0.f;
#pragma unroll
        for (int j = 0; j < 8; ++j) s += v[j];
        for (int off = 32; off > 0; off >>= 1) s += __shfl_xor(s, off);

        float theta = (s - 1.f) * (1.f / 512.f);
        int cnt = K_;
        for (int it = 0; it < K_; ++it) {
            float ls = 0.f; int lc = 0;
#pragma unroll
            for (int j = 0; j < 8; ++j)
                if (v[j] > theta) { ls += v[j]; ++lc; }
            for (int off = 32; off > 0; off >>= 1) {
                ls += __shfl_xor(ls, off);
                lc += __shfl_xor(lc, off);
            }
            if (lc == cnt) break;
            theta = (ls - 1.f) / (float)lc;
            cnt = lc;
        }
#pragma unroll
        for (int j = 0; j < 8; ++j) {
            const float o = fmaxf(v[j] - theta, 0.f);
            P[base + j * 64] = o;
            Ph[base + j * 64] = rne16(o);
            psum[j] += o;
        }
    }
#pragma unroll
    for (int j = 0; j < 8; ++j) ps[wave][lane + j * 64] = psum[j];
    __syncthreads();
    for (int c = threadIdx.x; c < 512; c += 1024) {
        float s = 0.f;
#pragma unroll
        for (int wv = 0; wv < 16; ++wv) s += ps[wv][c];
        part[(size_t)blockIdx.x * K_ + c] = s;
    }
}

// part[256][512] -> part2[16][512]
__global__ __launch_bounds__(512)
void part_reduce(const float* __restrict__ part, float* __restrict__ part2)
{
    const int t = threadIdx.x, b = blockIdx.x;
    float s = 0.f;
    for (int r = 0; r < 16; ++r) s += part[(size_t)(b * 16 + r) * K_ + t];
    part2[(size_t)b * K_ + t] = s;
}

// ---------------- finalize: scalars only -------------------------------------
#define BLOCK_REDUCE_512(val, result) \
    red[t] = (val); __syncthreads(); \
    for (int s_ = 256; s_ > 0; s_ >>= 1) { if (t < s_) red[t] += red[t + s_]; __syncthreads(); } \
    result = red[0]; __syncthreads();

__global__ __launch_bounds__(512)
void finalize_kernel(const float* __restrict__ part2, const float* __restrict__ divPart,
                     const float* __restrict__ lossPart, float* __restrict__ out_scal)
{
    __shared__ float red[512];
    const int t = threadIdx.x;

    float praw = 0.f;
    for (int b = 0; b < 16; ++b) praw += part2[b * K_ + t];
    const float pm = praw * (1.f / 32768.f);

    const float pj = fminf(fmaxf(pm, 1e-10f), 1.0f);
    float sp; BLOCK_REDUCE_512(pj, sp);
    const float pjn = pj / sp;
    float Hbits; BLOCK_REDUCE_512(-pjn * logf(pjn) / 0.69314718056f, Hbits);

    float spm; BLOCK_REDUCE_512(pm, spm);
    const float s2 = spm + 1e-5f;
    const float pmn = pm / s2;
    float ereg; BLOCK_REDUCE_512(-pmn * logf(pmn + 1e-5f), ereg);

    float dv = (t < 256) ? divPart[t] : 0.f;
    float divs; BLOCK_REDUCE_512(dv, divs);
    const float divloss = divs * (1.f / 262144.f);

    float lp = lossPart[t];
    float prim; BLOCK_REDUCE_512(lp, prim);
    prim *= 1.f / 8388608.f;

    if (t == 0) {
        out_scal[0] = prim + 0.5f * ereg + 0.5f * divloss;
        out_scal[1] = exp2f(Hbits);
    }
}

// ---------------- launch -----------------------------------------------------
extern "C" void kernel_launch(void* const* d_in, const int* in_sizes, int n_in,
                              void* d_out, int out_size, void* d_ws, size_t ws_size,
                              hipStream_t stream)
{
    const float* inputs = (const float*)d_in[0];
    const float* gamma  = (const float*)d_in[1];
    const float* beta   = (const float*)d_in[2];
    const float* C      = (const float*)d_in[3];
    const float* d_w    = (const float*)d_in[4];
    const float* d_b    = (const float*)d_in[5];

    float* out = (float*)d_out;
    float* Z = out;
    float* P = out + (size_t)M_ * D_;
    float* out_scal = P + (size_t)M_ * K_;

    float* w = (float*)d_ws;
    float* Sp   = w;     w += 4 * 65536;
    float* Tp   = w;     w += 4 * 65536;
    float* XpA  = w;     w += 4 * 65536;
    float* XpB  = w;     w += 4 * 65536;
    float* Up   = w;     w += 4 * 131072;
    float* Ap   = w;     w += 4 * 262144;
    float* Gp   = w;     w += 4 * 262144;
    float* Ainv = w;     w += 262144;
    float* Ct   = w;     w += 131072;
    float* cn2  = w;     w += 512;
    float* rowAbs = w;   w += 256;
    float* zn2  = w;     w += M_;
    float* part = w;     w += 256 * K_;
    float* part2 = w;    w += 16 * K_;
    float* lossPart = w; w += 512;
    float* divPart  = w; w += 256;
    float* PV   = w;     w += M_ * 4;
    float* PB   = w;     w += M_ * 4;
    int* PI     = (int*)w; w += M_ * 4;
    int* rlist  = (int*)w; w += M_;
    int* rcount = (int*)w; w += 16;
    int* assign = (int*)w; w += M_;
    unsigned short* Zh  = (unsigned short*)w; w += M_ * D_ / 2;
    unsigned short* Zl  = (unsigned short*)w; w += M_ * D_ / 2;
    unsigned short* Cth = (unsigned short*)w; w += (K_ * D_) / 2;
    unsigned short* Ctl = (unsigned short*)w; w += (K_ * D_) / 2;
    unsigned short* Ch  = (unsigned short*)w; w += (K_ * D_) / 2;
    unsigned short* Uth = (unsigned short*)w; w += (K_ * D_) / 2;
    unsigned short* Ph  = Zh;   // 32MB, aliases Zh+Zl (dead after mfma<2>)

    // 1. Z = LN(inputs @ d_w + d_b), zn2, Zh/Zl planes
    dense_ln_kernel<<<M_/64, 256, 0, stream>>>(inputs, d_w, d_b, gamma, beta, Z, zn2, Zh, Zl);
    // 2. prep: Ct + planes + Ch + cn2 + rcount=0
    prep_c<<<K_, 256, 0, stream>>>(C, Ct, Cth, Ctl, Ch, cn2, rcount);
    // 3. S partials = C C^T (split-K)
    sk_gemm<1, 0, 0, 0><<<dim3(4, 4, 4), 256, 0, stream>>>(Ct, Ct, Sp, 256, 256, 512, nullptr);
    // 4. NS init
    rowabs_kernel<<<256, 256, 0, stream>>>(Sp, rowAbs);
    x1_init<<<256, 256, 0, stream>>>(rowAbs, Sp, XpA);
    // 5. Newton-Schulz x3 with virtual X
    float* Xc = XpA; float* Xn = XpB;
    for (int it = 0; it < 3; ++it) {
        sk_gemm<0, 2, 1, 0><<<dim3(4, 4, 4), 256, 0, stream>>>(Sp, Xc, Tp, 256, 256, 256, nullptr);
        sk_gemm<0, 1, 1, 1><<<dim3(4, 4, 4), 256, 0, stream>>>(Xc, Tp, Xn, 256, 256, 256, Xc);
        float* tmp = Xc; Xc = Xn; Xn = tmp;
    }
    // 6. Ut partials; Ainv partials + reduce; G partials; merged reduces
    sk_gemm<1, 0, 1, 0><<<dim3(4, 8, 4), 256, 0, stream>>>(C, Xc, Up, 512, 256, 256, nullptr);
    sk_gemm<0, 1, 0, 0><<<dim3(8, 8, 4), 256, 0, stream>>>(Up, C, Ap, 512, 512, 256, nullptr);
    ainv_reduce<<<1024, 256, 0, stream>>>(Ap, Ainv);
    sk_gemm<1, 0, 0, 0><<<dim3(8, 8, 4), 256, 0, stream>>>(C, C, Gp, 512, 512, 256, nullptr);
    gut_reduce<<<768, 256, 0, stream>>>(Up, Uth, Gp, cn2, divPart);
    // 7. score (x3 MFMA on planes) + top-2 -> assign + repair set (parallel)
    score_mfma_argmin<<<dim3(K_/128, M_/128), 256, 0, stream>>>(Zh, Zl, Cth, Ctl, cn2, zn2, PV, PB, PI);
    argmin_reduce4<<<M_/256, 256, 0, stream>>>(PV, PB, PI, assign, rlist, rcount);
    repair_gemm<<<dim3(4, M_/128), 256, 0, stream>>>(Z, C, cn2, zn2, rlist, rcount, PV, PI);
    repair_scatter<<<M_/256, 256, 0, stream>>>(PV, PI, rlist, rcount, assign);
    // 8. P_sol^T = Z @ Ut^T + Ainv[assign,:]
    mfma_gemm<2><<<dim3(K_/128, M_/128), 256, 0, stream>>>(
        Zh, Uth, P, D_, K_, Ainv, assign, nullptr, nullptr);
    // 9. simplex projection + column sums + Ph plane
    project_colsum_kernel<<<M_/128, 1024, 0, stream>>>(P, Ph, part);
    part_reduce<<<16, 512, 0, stream>>>(part, part2);
    // 10. Zq = P @ C^T (Ph x Ch planes), loss partials
    mfma_gemm<3><<<dim3(D_/128, M_/128), 256, 0, stream>>>(
        Ph, Ch, Z, K_, D_, nullptr, nullptr, Z, lossPart);
    // 11. scalars
    finalize_kernel<<<1, 512, 0, stream>>>(part2, divPart, lossPart, out_scal);

    (void)in_sizes; (void)n_in; (void)out_size; (void)ws_size;
}